// Round 4
// baseline (453.272 us; speedup 1.0000x reference)
//
#include <hip/hip_runtime.h>
#include <hip/hip_bf16.h>
#include <math.h>

typedef __bf16 bf16_t;
typedef __bf16 bf16x8 __attribute__((ext_vector_type(8)));
typedef float f32x4 __attribute__((ext_vector_type(4)));

// ---------------------------------------------------------------------------
// Problem constants: B=4, H=64, W=128, C=512, F=1024, WS=4, SS=2, NH=8, hd=64.
// M = 32768 token rows. 2048 windows total.
// ---------------------------------------------------------------------------

#define X1_OFF   0u            // x1 fp32 residual [32768,512] = 64 MB
#define XW_OFF   67108864u     // xw -> O -> h2 (bf16, 32 MB)
#define QKV_OFF  100663296u    // qkv -> gelu-out a (bf16, 96 MB)
#define WQ_OFF   201326592u
#define WP_OFF   202899456u
#define W1_OFF   203423744u
#define W2_OFF   204472320u
#define SV_OFF   205520896u
#define FLAG_OFF 205545472u
// SV float offsets: g1=0 be1=512 bq=1024 bp=2560 g2=3072 be2=3584 b1=4096
//                   b2=5120 rpb=5632 (end 6024)

__device__ __forceinline__ int perm_row(int r) {
    int b   = r >> 13;
    int rem = r & 8191;
    int w   = rem >> 4;
    int n   = rem & 15;
    int wy  = w >> 5, wx = w & 31;
    int y   = wy * 4 + (n >> 2);
    int x   = wx * 4 + (n & 3);
    int ys  = (y + 2) & 63;
    int xs  = (x + 2) & 127;
    return (b << 13) + (ys << 7) + xs;
}

// global->LDS direct load, 16 B per lane: per-lane global addr + wave-uniform
// LDS base; HW scatters lane i -> base + i*16.
__device__ __forceinline__ void gld16(const void* g, void* l) {
    __builtin_amdgcn_global_load_lds(
        (const __attribute__((address_space(1))) unsigned int*)(unsigned long long)(uintptr_t)g,
        (__attribute__((address_space(3))) unsigned int*)(unsigned int)(uintptr_t)l,
        16, 0, 0);
}

#define SBAR __builtin_amdgcn_sched_barrier(0)
#define BARRIER do { SBAR; __builtin_amdgcn_s_barrier(); SBAR; } while (0)

// ---------------- dtype probe: 1 = fp32 source, 0 = bf16 source ----------------
__global__ __launch_bounds__(256) void k_probe(const unsigned short* __restrict__ x,
                                               int n, int* __restrict__ flag) {
    __shared__ int cnt;
    if (threadIdx.x == 0) cnt = 0;
    __syncthreads();
    int c = 0;
    for (int i = threadIdx.x; i < n; i += 256) {
        int e = (x[i] >> 7) & 0xFF;
        if (e >= 0xC0) c++;
    }
    atomicAdd(&cnt, c);
    __syncthreads();
    if (threadIdx.x == 0) *flag = (cnt > 8) ? 1 : 0;
}

// ---------------- weight / small-vector normalization ----------------
__global__ __launch_bounds__(256) void k_cvt_bf16(const void* __restrict__ src,
                                                  bf16_t* __restrict__ dst, int n,
                                                  const int* __restrict__ flag) {
    int i = blockIdx.x * 256 + threadIdx.x;
    if (i >= n) return;
    dst[i] = (*flag) ? (bf16_t)((const float*)src)[i] : ((const bf16_t*)src)[i];
}

__global__ __launch_bounds__(256) void k_cvt_small(
        const void* g1, const void* be1, const void* bq, const void* bp,
        const void* g2, const void* be2, const void* b1, const void* b2,
        const void* rpb, float* __restrict__ dst, const int* __restrict__ flag) {
    int i = blockIdx.x * 256 + threadIdx.x;
    const void* src; int off;
    if      (i < 512)  { src = g1;  off = i; }
    else if (i < 1024) { src = be1; off = i - 512; }
    else if (i < 2560) { src = bq;  off = i - 1024; }
    else if (i < 3072) { src = bp;  off = i - 2560; }
    else if (i < 3584) { src = g2;  off = i - 3072; }
    else if (i < 4096) { src = be2; off = i - 3584; }
    else if (i < 5120) { src = b1;  off = i - 4096; }
    else if (i < 5632) { src = b2;  off = i - 5120; }
    else if (i < 6024) { src = rpb; off = i - 5632; }
    else return;
    dst[i] = (*flag) ? ((const float*)src)[off] : (float)((const bf16_t*)src)[off];
}

// ---------------- Kernel 1: LN1 + shift + window partition ----------------
__global__ __launch_bounds__(256) void k_ln1(const void* __restrict__ x,
                                             const float* __restrict__ g,
                                             const float* __restrict__ be,
                                             bf16_t* __restrict__ xw,
                                             const int* __restrict__ flag) {
    int r    = blockIdx.x * 4 + (threadIdx.x >> 6);
    int lane = threadIdx.x & 63;
    int f    = *flag;
    long ro  = (long)perm_row(r) * 512;
    const float*  x32 = (const float*)x + ro;
    const bf16_t* x16 = (const bf16_t*)x + ro;
    int base = lane * 8;
    float v[8];
    float s = 0.f, ss = 0.f;
#pragma unroll
    for (int j = 0; j < 8; j++) {
        float t = f ? x32[base + j] : (float)x16[base + j];
        v[j] = t; s += t; ss += t * t;
    }
#pragma unroll
    for (int off = 32; off; off >>= 1) {
        s  += __shfl_down(s,  off, 64);
        ss += __shfl_down(ss, off, 64);
    }
    s  = __shfl(s, 0, 64);
    ss = __shfl(ss, 0, 64);
    float m   = s * (1.f / 512.f);
    float var = ss * (1.f / 512.f) - m * m;
    float inv = rsqrtf(var + 1e-5f);
    bf16_t* orow = xw + (long)r * 512;
#pragma unroll
    for (int j = 0; j < 8; j++)
        orow[base + j] = (bf16_t)((v[j] - m) * inv * g[base + j] + be[base + j]);
}

// ---------------- Kernel 5: LN2 ----------------
__global__ __launch_bounds__(256) void k_ln2(const float* __restrict__ x1,
                                             const float* __restrict__ g,
                                             const float* __restrict__ be,
                                             bf16_t* __restrict__ h2) {
    int r    = blockIdx.x * 4 + (threadIdx.x >> 6);
    int lane = threadIdx.x & 63;
    const float* xr = x1 + (long)r * 512;
    int base = lane * 8;
    float v[8];
    float s = 0.f, ss = 0.f;
#pragma unroll
    for (int j = 0; j < 8; j++) {
        float t = xr[base + j];
        v[j] = t; s += t; ss += t * t;
    }
#pragma unroll
    for (int off = 32; off; off >>= 1) {
        s  += __shfl_down(s,  off, 64);
        ss += __shfl_down(ss, off, 64);
    }
    s  = __shfl(s, 0, 64);
    ss = __shfl(ss, 0, 64);
    float m   = s * (1.f / 512.f);
    float var = ss * (1.f / 512.f) - m * m;
    float inv = rsqrtf(var + 1e-5f);
    bf16_t* orow = h2 + (long)r * 512;
#pragma unroll
    for (int j = 0; j < 8; j++)
        orow[base + j] = (bf16_t)((v[j] - m) * inv * g[base + j] + be[base + j]);
}

// ---------------- 256x256-tile GEMM, 8-phase counted-vmcnt schedule --------
// v4: reads-early single-barrier phases (m201 rhythm).
// C = A @ W^T.  8 waves (wh=M-half, wq=N-quarter); wave owns C rows
// {wh*64..} U {128+wh*64..}, cols {wq*32..} U {128+wq*32..} -> uniform
// residency: ph0:(Al,Bl) ph1:(Al,Bh) ph2:(Ah,Bl) ph3:(Ah,Bh), 16 MFMA each.
// K-tile (BK=64) = 4 slots x 16 KB, double-buffered (2 x 64 KB).
//
// Phase = { ds_read frags (data resident since PREVIOUS phase's barrier)
//           ∥ stage 1 half-tile of t+1 -> vmcnt(4) -> s_barrier ->
//           lgkmcnt(0) -> setprio(1) 16 MFMA setprio(0) }.
// ds_read latency hides under the vmcnt+barrier wait; ONE barrier/phase.
// vmcnt ledger (2 loads/stage/thread, stage order Al,Bl,Bh,Ah):
//   entering ph0: {Bh(t),Ah(t)} in flight (4).  ph0: +Al(t+1) -> vmcnt(4)
//   completes Bh(t) (needed ph1).  ph1: +Bl(t+1) -> vmcnt(4) completes
//   Ah(t) (needed ph2).  ph2: +Bh(t+1), no wait.  ph3: +Ah(t+1) ->
//   vmcnt(4) completes Al,Bl(t+1) (needed t+1 ph0).  NEVER 0 in main loop.
//   Tail: vmcnt(2)/vmcnt(0) at ph0/ph1.  WAR on slot reuse: each stage is
//   >=3 barriers after the last ds_read of that slot (reads drain via each
//   wave's own lgkmcnt(0) before it reaches the next barrier).
// LDS swizzle: 16B chunk c of row r at c ^ (r&7) via pre-swizzled GLOBAL
// source (LDS dest linear, as global_load_lds requires).
// EPI: 0=bias->bf16  1=proj: x1[perm]=x+acc+bias (fp32)  2=bias+GELU->bf16
//      3=fc2: out=x1+acc+bias (flag dtype)
template<int EPI>
__global__ __launch_bounds__(512, 2) void k_gemm256(const bf16_t* __restrict__ A,
                                                    const bf16_t* __restrict__ Wt,
                                                    const float* __restrict__ bias,
                                                    void* __restrict__ out,
                                                    const void* __restrict__ res,
                                                    const int* __restrict__ flag,
                                                    int N, int K) {
    __shared__ __attribute__((aligned(16))) char smem[131072];
    int tid  = threadIdx.x;
    int lane = tid & 63, wv = tid >> 6;

    int nbx = N >> 8;
    int id  = blockIdx.x;
    int xb  = (id >> 3) % nbx;
    int yb  = ((id >> 3) / nbx) * 8 + (id & 7);
    int m0  = yb << 8, n0 = xb << 8;

    // ---- staging addressing ----
    int srow = tid >> 3;                       // 0..63
    int cg   = (tid & 7) ^ (srow & 7);         // pre-swizzled 16B chunk
    const bf16_t* gA = A  + (long)(m0 + srow) * K + cg * 8;
    const bf16_t* gB = Wt + (long)(n0 + srow) * K + cg * 8;
    long r64 = (long)64 * K;

    // ---- fragment geometry ----
    int rr = lane & 15, quad = lane >> 4;
    int wh = wv >> 2, wq = wv & 3;
    int lA  = (wh * 64 + rr) * 128;            // byte offset in A slot
    int lB  = (wq * 32 + rr) * 128;            // byte offset in B slot
    int ck0 = (quad ^ (rr & 7)) * 16;          // kk=0 chunk byte offset
    int ck1 = ck0 ^ 64;                        // kk=1

    f32x4 acc[8][4];
#pragma unroll
    for (int mi = 0; mi < 8; mi++)
#pragma unroll
        for (int ni = 0; ni < 4; ni++) { f32x4 z = {0.f,0.f,0.f,0.f}; acc[mi][ni] = z; }

    int S = K >> 6;   // #K-tiles (8 or 16)

    // prologue: stage tile 0, order [Al, Bl, Bh, Ah]; publish Al,Bl
    gld16(gA,             smem + 0     + wv * 1024);
    gld16(gA + r64,       smem + 8192  + wv * 1024);
    gld16(gB,             smem + 32768 + wv * 1024);
    gld16(gB + r64,       smem + 40960 + wv * 1024);
    gld16(gB + 2 * r64,   smem + 49152 + wv * 1024);
    gld16(gB + 3 * r64,   smem + 57344 + wv * 1024);
    gld16(gA + 2 * r64,   smem + 16384 + wv * 1024);
    gld16(gA + 3 * r64,   smem + 24576 + wv * 1024);
    asm volatile("s_waitcnt vmcnt(4)" ::: "memory");
    BARRIER;

    bf16x8 af[4][2], bg[2][2];

#define FRAG_A(AH)                                                            \
    _Pragma("unroll") for (int mi = 0; mi < 4; mi++) {                        \
        af[mi][0] = *(const bf16x8*)(bc + (AH)*16384 + lA + mi*2048 + ck0);   \
        af[mi][1] = *(const bf16x8*)(bc + (AH)*16384 + lA + mi*2048 + ck1);   \
    }
#define FRAG_B(BH)                                                            \
    _Pragma("unroll") for (int ni = 0; ni < 2; ni++) {                        \
        bg[ni][0] = *(const bf16x8*)(bc + 32768 + (BH)*16384 + lB + ni*2048 + ck0); \
        bg[ni][1] = *(const bf16x8*)(bc + 32768 + (BH)*16384 + lB + ni*2048 + ck1); \
    }
#define MFMA_CL(AH, BH)                                                       \
    do {                                                                      \
        asm volatile("s_waitcnt lgkmcnt(0)" ::: "memory"); SBAR;              \
        __builtin_amdgcn_s_setprio(1);                                        \
        _Pragma("unroll") for (int mi = 0; mi < 4; mi++)                      \
            _Pragma("unroll") for (int ni = 0; ni < 2; ni++)                  \
                _Pragma("unroll") for (int kk = 0; kk < 2; kk++)              \
                    acc[(AH)*4 + mi][(BH)*2 + ni] =                           \
                        __builtin_amdgcn_mfma_f32_16x16x32_bf16(              \
                            af[mi][kk], bg[ni][kk], acc[(AH)*4 + mi][(BH)*2 + ni], 0, 0, 0); \
        __builtin_amdgcn_s_setprio(0);                                        \
    } while (0)
#define STAGE(GP, SLOT)                                                       \
    do { gld16((GP) + kn,       bn + (SLOT) + wv * 1024);                     \
         gld16((GP) + r64 + kn, bn + (SLOT) + 8192 + wv * 1024); } while (0)

    for (int t = 0; t < S; ++t) {
        char* bc = smem + (t & 1) * 65536;
        char* bn = smem + ((t & 1) ^ 1) * 65536;
        long  kn = (long)(t + 1) * 64;
        bool  st = (t + 1 < S);
        // ---- phase 0: (Al,Bl); stage Al(t+1) ----
        FRAG_A(0); FRAG_B(0);
        if (st) { STAGE(gA, 0);
                  asm volatile("s_waitcnt vmcnt(4)" ::: "memory"); }
        else    { asm volatile("s_waitcnt vmcnt(2)" ::: "memory"); }
        BARRIER;
        MFMA_CL(0, 0);
        // ---- phase 1: (Al,Bh); stage Bl(t+1) ----
        FRAG_B(1);
        if (st) { STAGE(gB, 32768);
                  asm volatile("s_waitcnt vmcnt(4)" ::: "memory"); }
        else    { asm volatile("s_waitcnt vmcnt(0)" ::: "memory"); }
        BARRIER;
        MFMA_CL(0, 1);
        // ---- phase 2: (Ah,Bl); stage Bh(t+1); no new residency ----
        FRAG_A(1); FRAG_B(0);
        if (st) STAGE(gB + 2 * r64, 49152);
        BARRIER;
        MFMA_CL(1, 0);
        // ---- phase 3: (Ah,Bh); stage Ah(t+1); publish Al,Bl(t+1) ----
        FRAG_B(1);
        if (st) { STAGE(gA + 2 * r64, 16384);
                  asm volatile("s_waitcnt vmcnt(4)" ::: "memory"); }
        BARRIER;
        MFMA_CL(1, 1);
    }
    // drain: every wave passed its own lgkmcnt(0) before arriving here ->
    // all LDS reads retired; scratch reuse below is safe.
    BARRIER;
#undef FRAG_A
#undef FRAG_B
#undef MFMA_CL
#undef STAGE

    // ---------------- vectorized epilogue via per-wave LDS transpose -------
    float* sc = (float*)(smem + wv * 16384);
    int f    = (EPI == 1 || EPI == 3) ? *flag : 0;
    int j8   = lane & 7;
    int rl   = lane >> 3;
    int colg = n0 + wq * 32 + (j8 >> 2) * 128 + ((j8 * 8) & 31);
    f32x4 b0 = *(const f32x4*)(bias + colg);
    f32x4 b1 = *(const f32x4*)(bias + colg + 4);

#pragma unroll
    for (int ah = 0; ah < 2; ++ah) {
        // scatter this ah-half's 64x64 into swizzled scratch
#pragma unroll
        for (int bh = 0; bh < 2; ++bh)
#pragma unroll
            for (int ni = 0; ni < 2; ++ni)
#pragma unroll
                for (int mi = 0; mi < 4; ++mi)
#pragma unroll
                    for (int i = 0; i < 4; ++i) {
                        int r  = mi * 16 + quad * 4 + i;
                        int cl = bh * 32 + ni * 16 + rr;
                        sc[r * 64 + ((((cl >> 2) ^ (r & 15)) << 2) | (cl & 3))] =
                            acc[ah * 4 + mi][bh * 2 + ni][i];
                    }
        // readback rows, 8 consecutive cols per lane, vector stores
#pragma unroll
        for (int p = 0; p < 8; ++p) {
            int r = p * 8 + rl;
            f32x4 v0 = *(const f32x4*)(sc + r * 64 + (((2 * j8)     ^ (r & 15)) << 2));
            f32x4 v1 = *(const f32x4*)(sc + r * 64 + (((2 * j8 + 1) ^ (r & 15)) << 2));
            int row = m0 + ah * 128 + wh * 64 + r;
            v0 += b0; v1 += b1;

            if (EPI == 0) {
                bf16x8 ob;
#pragma unroll
                for (int c = 0; c < 4; c++) { ob[c] = (bf16_t)v0[c]; ob[c + 4] = (bf16_t)v1[c]; }
                *(bf16x8*)((bf16_t*)out + (long)row * N + colg) = ob;
            } else if (EPI == 1) {
                long o = (long)perm_row(row) * 512 + colg;
                if (f) {
                    f32x4 r0 = *(const f32x4*)((const float*)res + o);
                    f32x4 r1 = *(const f32x4*)((const float*)res + o + 4);
                    v0 += r0; v1 += r1;
                } else {
                    bf16x8 rb = *(const bf16x8*)((const bf16_t*)res + o);
#pragma unroll
                    for (int c = 0; c < 4; c++) { v0[c] += (float)rb[c]; v1[c] += (float)rb[c + 4]; }
                }
                *(f32x4*)((float*)out + o)     = v0;
                *(f32x4*)((float*)out + o + 4) = v1;
            } else if (EPI == 2) {
                bf16x8 ob;
#pragma unroll
                for (int c = 0; c < 4; c++) {
                    float a0 = v0[c], a1 = v1[c];
                    ob[c]     = (bf16_t)(0.5f * a0 * (1.f + erff(a0 * 0.70710678118654752f)));
                    ob[c + 4] = (bf16_t)(0.5f * a1 * (1.f + erff(a1 * 0.70710678118654752f)));
                }
                *(bf16x8*)((bf16_t*)out + (long)row * N + colg) = ob;
            } else {
                long o = (long)row * 512 + colg;
                f32x4 r0 = *(const f32x4*)((const float*)res + o);
                f32x4 r1 = *(const f32x4*)((const float*)res + o + 4);
                v0 += r0; v1 += r1;
                if (f) {
                    *(f32x4*)((float*)out + o)     = v0;
                    *(f32x4*)((float*)out + o + 4) = v1;
                } else {
                    bf16x8 ob;
#pragma unroll
                    for (int c = 0; c < 4; c++) { ob[c] = (bf16_t)v0[c]; ob[c + 4] = (bf16_t)v1[c]; }
                    *(bf16x8*)((bf16_t*)out + o) = ob;
                }
            }
        }
    }
}

// ---------------- Kernel 3: windowed attention ----------------
__global__ __launch_bounds__(256) void k_attn(const bf16_t* __restrict__ qkv,
                                              const float* __restrict__ rpb,
                                              bf16_t* __restrict__ O) {
    __shared__ float q[16][68], k[16][68], v[16][68];
    __shared__ float S[16][17];

    int blk = blockIdx.x;
    int h   = blk & 7;
    int w   = blk >> 3;
    int tid = threadIdx.x;

    int n0 = tid >> 4;
    int d0 = (tid & 15) * 4;
    const bf16_t* base = qkv + (long)(w * 16 + n0) * 1536 + h * 64 + d0;
#pragma unroll
    for (int j = 0; j < 4; j++) {
        q[n0][d0 + j] = (float)base[j] * 0.125f;
        k[n0][d0 + j] = (float)base[512 + j];
        v[n0][d0 + j] = (float)base[1024 + j];
    }
    __syncthreads();

    int i = tid >> 4, j = tid & 15;
    float s = 0.f;
#pragma unroll
    for (int d = 0; d < 64; d++) s += q[i][d] * k[j][d];

    int iy = i >> 2, ix = i & 3, jy = j >> 2, jx = j & 3;
    s += rpb[((iy - jy + 3) * 7 + (ix - jx + 3)) * 8 + h];

    int wl = w & 511;
    int wy = wl >> 5, wx = wl & 31;
    int yi = wy * 4 + iy, xi = wx * 4 + ix;
    int yj = wy * 4 + jy, xj = wx * 4 + jx;
    int ri = (yi < 60 ? 0 : (yi < 62 ? 1 : 2)) * 3 + (xi < 124 ? 0 : (xi < 126 ? 1 : 2));
    int rj = (yj < 60 ? 0 : (yj < 62 ? 1 : 2)) * 3 + (xj < 124 ? 0 : (xj < 126 ? 1 : 2));
    if (ri != rj) s -= 100.f;
    S[i][j] = s;
    __syncthreads();

    if (tid < 16) {
        float mx = -1e30f;
#pragma unroll
        for (int c = 0; c < 16; c++) mx = fmaxf(mx, S[tid][c]);
        float sum = 0.f;
#pragma unroll
        for (int c = 0; c < 16; c++) { float e = expf(S[tid][c] - mx); S[tid][c] = e; sum += e; }
        float invs = 1.f / sum;
#pragma unroll
        for (int c = 0; c < 16; c++) S[tid][c] *= invs;
    }
    __syncthreads();

#pragma unroll
    for (int t = 0; t < 4; t++) {
        int e  = tid + t * 256;
        int oi = e >> 6, od = e & 63;
        float acc = 0.f;
#pragma unroll
        for (int c = 0; c < 16; c++) acc += S[oi][c] * v[c][od];
        O[(long)(w * 16 + oi) * 512 + h * 64 + od] = (bf16_t)acc;
    }
}

// ---------------------------------------------------------------------------
extern "C" void kernel_launch(void* const* d_in, const int* in_sizes, int n_in,
                              void* d_out, int out_size, void* d_ws, size_t ws_size,
                              hipStream_t stream) {
    char* ws = (char*)d_ws;
    float*  x1   = (float*)(ws + X1_OFF);
    bf16_t* xw   = (bf16_t*)(ws + XW_OFF);    // xw -> O -> h2
    bf16_t* qkv  = (bf16_t*)(ws + QKV_OFF);   // qkv -> gelu-out a
    bf16_t* wq_b = (bf16_t*)(ws + WQ_OFF);
    bf16_t* wp_b = (bf16_t*)(ws + WP_OFF);
    bf16_t* w1_b = (bf16_t*)(ws + W1_OFF);
    bf16_t* w2_b = (bf16_t*)(ws + W2_OFF);
    float*  sv   = (float*)(ws + SV_OFF);
    int*    flag = (int*)(ws + FLAG_OFF);

    k_probe<<<1, 256, 0, stream>>>((const unsigned short*)d_in[0], 4096, flag);
    k_cvt_bf16<<<3072, 256, 0, stream>>>(d_in[3],  wq_b, 786432, flag);
    k_cvt_bf16<<<1024, 256, 0, stream>>>(d_in[6],  wp_b, 262144, flag);
    k_cvt_bf16<<<2048, 256, 0, stream>>>(d_in[10], w1_b, 524288, flag);
    k_cvt_bf16<<<2048, 256, 0, stream>>>(d_in[12], w2_b, 524288, flag);
    k_cvt_small<<<24,  256, 0, stream>>>(d_in[1], d_in[2], d_in[4], d_in[7],
                                         d_in[8], d_in[9], d_in[11], d_in[13],
                                         d_in[5], sv, flag);

    k_ln1<<<dim3(8192), dim3(256), 0, stream>>>(d_in[0], sv, sv + 512, xw, flag);
    k_gemm256<0><<<dim3(768), dim3(512), 0, stream>>>(xw, wq_b, sv + 1024, qkv, nullptr, flag, 1536, 512);
    k_attn<<<dim3(16384), dim3(256), 0, stream>>>(qkv, sv + 5632, xw /*O*/);
    k_gemm256<1><<<dim3(256), dim3(512), 0, stream>>>(xw, wp_b, sv + 2560, x1, d_in[0], flag, 512, 512);
    k_ln2<<<dim3(8192), dim3(256), 0, stream>>>(x1, sv + 3072, sv + 3584, xw /*h2*/);
    k_gemm256<2><<<dim3(512), dim3(512), 0, stream>>>(xw, w1_b, sv + 4096, qkv /*a*/, nullptr, flag, 1024, 512);
    k_gemm256<3><<<dim3(256), dim3(512), 0, stream>>>(qkv, w2_b, sv + 5120, d_out, x1, flag, 512, 1024);
}

// Round 5
// 427.847 us; speedup vs baseline: 1.0594x; 1.0594x over previous
//
#include <hip/hip_runtime.h>
#include <hip/hip_bf16.h>
#include <math.h>

typedef __bf16 bf16_t;
typedef __bf16 bf16x8 __attribute__((ext_vector_type(8)));
typedef __bf16 bf16x4 __attribute__((ext_vector_type(4)));
typedef float f32x4 __attribute__((ext_vector_type(4)));

// ---------------------------------------------------------------------------
// Problem constants: B=4, H=64, W=128, C=512, F=1024, WS=4, SS=2, NH=8, hd=64.
// M = 32768 token rows. 2048 windows total.
// ---------------------------------------------------------------------------

#define X1_OFF   0u            // x1 fp32 residual [32768,512] = 64 MB
#define XW_OFF   67108864u     // xw -> O -> h2 (bf16, 32 MB)
#define QKV_OFF  100663296u    // qkv -> gelu-out a (bf16, 96 MB)
#define WQ_OFF   201326592u
#define WP_OFF   202899456u
#define W1_OFF   203423744u
#define W2_OFF   204472320u
#define SV_OFF   205520896u
#define FLAG_OFF 205545472u
// SV float offsets: g1=0 be1=512 bq=1024 bp=2560 g2=3072 be2=3584 b1=4096
//                   b2=5120 rpb=5632 (end 6024)

__device__ __forceinline__ int perm_row(int r) {
    int b   = r >> 13;
    int rem = r & 8191;
    int w   = rem >> 4;
    int n   = rem & 15;
    int wy  = w >> 5, wx = w & 31;
    int y   = wy * 4 + (n >> 2);
    int x   = wx * 4 + (n & 3);
    int ys  = (y + 2) & 63;
    int xs  = (x + 2) & 127;
    return (b << 13) + (ys << 7) + xs;
}

// global->LDS direct load, 16 B per lane: per-lane global addr + wave-uniform
// LDS base; HW scatters lane i -> base + i*16.
__device__ __forceinline__ void gld16(const void* g, void* l) {
    __builtin_amdgcn_global_load_lds(
        (const __attribute__((address_space(1))) unsigned int*)(unsigned long long)(uintptr_t)g,
        (__attribute__((address_space(3))) unsigned int*)(unsigned int)(uintptr_t)l,
        16, 0, 0);
}

#define SBAR __builtin_amdgcn_sched_barrier(0)
#define BARRIER do { SBAR; __builtin_amdgcn_s_barrier(); SBAR; } while (0)

// fast GELU: 0.5x(1+tanh(0.79788456(x+0.044715x^3))), tanh via exp2.
// |gelu_tanh - gelu_erf| <= ~1e-3, far inside the 0.03125 abs tolerance.
__device__ __forceinline__ float fast_gelu(float x) {
    float y = 0.7978845608f * (x + 0.044715f * x * x * x);
    y = fminf(fmaxf(y, -15.f), 15.f);
    float u = __builtin_amdgcn_exp2f(y * 2.885390082f);   // e^{2y}
    float t = (u - 1.f) / (u + 1.f);                       // tanh(y)
    return 0.5f * x * (1.f + t);
}

// ---------------- dtype probe: 1 = fp32 source, 0 = bf16 source ----------------
__global__ __launch_bounds__(256) void k_probe(const unsigned short* __restrict__ x,
                                               int n, int* __restrict__ flag) {
    __shared__ int cnt;
    if (threadIdx.x == 0) cnt = 0;
    __syncthreads();
    int c = 0;
    for (int i = threadIdx.x; i < n; i += 256) {
        int e = (x[i] >> 7) & 0xFF;
        if (e >= 0xC0) c++;
    }
    atomicAdd(&cnt, c);
    __syncthreads();
    if (threadIdx.x == 0) *flag = (cnt > 8) ? 1 : 0;
}

// ---------------- weight / small-vector normalization ----------------
__global__ __launch_bounds__(256) void k_cvt_bf16(const void* __restrict__ src,
                                                  bf16_t* __restrict__ dst, int n,
                                                  const int* __restrict__ flag) {
    int i = blockIdx.x * 256 + threadIdx.x;
    if (i >= n) return;
    if (*flag) dst[i] = (bf16_t)((const float*)src)[i];
    else       dst[i] = ((const bf16_t*)src)[i];
}

__global__ __launch_bounds__(256) void k_cvt_small(
        const void* g1, const void* be1, const void* bq, const void* bp,
        const void* g2, const void* be2, const void* b1, const void* b2,
        const void* rpb, float* __restrict__ dst, const int* __restrict__ flag) {
    int i = blockIdx.x * 256 + threadIdx.x;
    const void* src; int off;
    if      (i < 512)  { src = g1;  off = i; }
    else if (i < 1024) { src = be1; off = i - 512; }
    else if (i < 2560) { src = bq;  off = i - 1024; }
    else if (i < 3072) { src = bp;  off = i - 2560; }
    else if (i < 3584) { src = g2;  off = i - 3072; }
    else if (i < 4096) { src = be2; off = i - 3584; }
    else if (i < 5120) { src = b1;  off = i - 4096; }
    else if (i < 5632) { src = b2;  off = i - 5120; }
    else if (i < 6024) { src = rpb; off = i - 5632; }
    else return;
    if (*flag) dst[i] = ((const float*)src)[off];
    else       dst[i] = (float)((const bf16_t*)src)[off];
}

// ---------------- Kernel 1: LN1 + shift + window partition ----------------
__global__ __launch_bounds__(256) void k_ln1(const void* __restrict__ x,
                                             const float* __restrict__ g,
                                             const float* __restrict__ be,
                                             bf16_t* __restrict__ xw,
                                             const int* __restrict__ flag) {
    int r    = blockIdx.x * 4 + (threadIdx.x >> 6);
    int lane = threadIdx.x & 63;
    long ro  = (long)perm_row(r) * 512;
    int base = lane * 8;
    float v[8];
    if (*flag) {
        const float* p = (const float*)x + ro + base;
#pragma unroll
        for (int j = 0; j < 8; j++) v[j] = p[j];
    } else {
        bf16x8 p = *(const bf16x8*)((const bf16_t*)x + ro + base);
#pragma unroll
        for (int j = 0; j < 8; j++) v[j] = (float)p[j];
    }
    float s = 0.f, ss = 0.f;
#pragma unroll
    for (int j = 0; j < 8; j++) { s += v[j]; ss += v[j] * v[j]; }
#pragma unroll
    for (int off = 32; off; off >>= 1) {
        s  += __shfl_down(s,  off, 64);
        ss += __shfl_down(ss, off, 64);
    }
    s  = __shfl(s, 0, 64);
    ss = __shfl(ss, 0, 64);
    float m   = s * (1.f / 512.f);
    float var = ss * (1.f / 512.f) - m * m;
    float inv = rsqrtf(var + 1e-5f);
    bf16_t* orow = xw + (long)r * 512;
    bf16x8 o;
#pragma unroll
    for (int j = 0; j < 8; j++)
        o[j] = (bf16_t)((v[j] - m) * inv * g[base + j] + be[base + j]);
    *(bf16x8*)(orow + base) = o;
}

// ---------------- Kernel 5: LN2 ----------------
__global__ __launch_bounds__(256) void k_ln2(const float* __restrict__ x1,
                                             const float* __restrict__ g,
                                             const float* __restrict__ be,
                                             bf16_t* __restrict__ h2) {
    int r    = blockIdx.x * 4 + (threadIdx.x >> 6);
    int lane = threadIdx.x & 63;
    const float* xr = x1 + (long)r * 512;
    int base = lane * 8;
    float v[8];
    float s = 0.f, ss = 0.f;
#pragma unroll
    for (int j = 0; j < 8; j++) {
        float t = xr[base + j];
        v[j] = t; s += t; ss += t * t;
    }
#pragma unroll
    for (int off = 32; off; off >>= 1) {
        s  += __shfl_down(s,  off, 64);
        ss += __shfl_down(ss, off, 64);
    }
    s  = __shfl(s, 0, 64);
    ss = __shfl(ss, 0, 64);
    float m   = s * (1.f / 512.f);
    float var = ss * (1.f / 512.f) - m * m;
    float inv = rsqrtf(var + 1e-5f);
    bf16_t* orow = h2 + (long)r * 512;
    bf16x8 o;
#pragma unroll
    for (int j = 0; j < 8; j++)
        o[j] = (bf16_t)((v[j] - m) * inv * g[base + j] + be[base + j]);
    *(bf16x8*)(orow + base) = o;
}

// ---------------- 256x256-tile GEMM, 8-phase counted-vmcnt schedule --------
// v5: serpentine phase order with fragment retention.
//   ph0:(Al,Bl)  ph1:(Al,Bh)  ph2:(Ah,Bh)  ph3:(Ah,Bl)
// Adjacent phases share one operand -> ph1 keeps af, ph2 keeps bg, ph3 keeps
// af: ds_read_b128 count drops 32 -> 24 per K-tile per wave (-25% LDS BW).
// vmcnt ledger (stage order Al,Bl,Bh,Ah; 2 loads/stage/thread) unchanged:
//   entering ph0: {Bh(t),Ah(t)} in flight (4).  ph0 +Al(t+1) -> vmcnt(4)
//   completes Bh(t) (needed ph1).  ph1 +Bl(t+1) -> vmcnt(4) completes Ah(t)
//   (needed ph2).  ph2 +Bh(t+1), no wait.  ph3 +Ah(t+1) -> vmcnt(4)
//   completes Al,Bl(t+1) (needed t+1 ph0).  NEVER 0 in main loop; tail 2/0.
//   WAR on slot reuse: each stage is >=2 barriers after the last ds_read of
//   that slot and every wave passes its own lgkmcnt(0) before the next
//   barrier -> reads retired before overwrite.
// LDS swizzle: 16B chunk c of row r at c ^ (r&7) via pre-swizzled GLOBAL
// source (LDS dest linear, as global_load_lds requires).
// EPI: 0=bias->bf16  1=proj: x1[perm]=x+acc+bias (fp32)  2=bias+GELU->bf16
//      3=fc2: out=x1+acc+bias (flag dtype)
template<int EPI>
__global__ __launch_bounds__(512, 2) void k_gemm256(const bf16_t* __restrict__ A,
                                                    const bf16_t* __restrict__ Wt,
                                                    const float* __restrict__ bias,
                                                    void* __restrict__ out,
                                                    const void* __restrict__ res,
                                                    const int* __restrict__ flag,
                                                    int N, int K) {
    __shared__ __attribute__((aligned(16))) char smem[131072];
    int tid  = threadIdx.x;
    int lane = tid & 63, wv = tid >> 6;

    int nbx = N >> 8;
    int id  = blockIdx.x;
    int xb  = (id >> 3) % nbx;
    int yb  = ((id >> 3) / nbx) * 8 + (id & 7);
    int m0  = yb << 8, n0 = xb << 8;

    // ---- staging addressing ----
    int srow = tid >> 3;                       // 0..63
    int cg   = (tid & 7) ^ (srow & 7);         // pre-swizzled 16B chunk
    const bf16_t* gA = A  + (long)(m0 + srow) * K + cg * 8;
    const bf16_t* gB = Wt + (long)(n0 + srow) * K + cg * 8;
    long r64 = (long)64 * K;

    // ---- fragment geometry ----
    int rr = lane & 15, quad = lane >> 4;
    int wh = wv >> 2, wq = wv & 3;
    int lA  = (wh * 64 + rr) * 128;            // byte offset in A slot
    int lB  = (wq * 32 + rr) * 128;            // byte offset in B slot
    int ck0 = (quad ^ (rr & 7)) * 16;          // kk=0 chunk byte offset
    int ck1 = ck0 ^ 64;                        // kk=1

    f32x4 acc[8][4];
#pragma unroll
    for (int mi = 0; mi < 8; mi++)
#pragma unroll
        for (int ni = 0; ni < 4; ni++) { f32x4 z = {0.f,0.f,0.f,0.f}; acc[mi][ni] = z; }

    int S = K >> 6;   // #K-tiles (8 or 16)

    // prologue: stage tile 0, order [Al, Bl, Bh, Ah]; publish Al,Bl
    gld16(gA,             smem + 0     + wv * 1024);
    gld16(gA + r64,       smem + 8192  + wv * 1024);
    gld16(gB,             smem + 32768 + wv * 1024);
    gld16(gB + r64,       smem + 40960 + wv * 1024);
    gld16(gB + 2 * r64,   smem + 49152 + wv * 1024);
    gld16(gB + 3 * r64,   smem + 57344 + wv * 1024);
    gld16(gA + 2 * r64,   smem + 16384 + wv * 1024);
    gld16(gA + 3 * r64,   smem + 24576 + wv * 1024);
    asm volatile("s_waitcnt vmcnt(4)" ::: "memory");
    BARRIER;

    bf16x8 af[4][2], bg[2][2];

#define FRAG_A(AH)                                                            \
    _Pragma("unroll") for (int mi = 0; mi < 4; mi++) {                        \
        af[mi][0] = *(const bf16x8*)(bc + (AH)*16384 + lA + mi*2048 + ck0);   \
        af[mi][1] = *(const bf16x8*)(bc + (AH)*16384 + lA + mi*2048 + ck1);   \
    }
#define FRAG_B(BH)                                                            \
    _Pragma("unroll") for (int ni = 0; ni < 2; ni++) {                        \
        bg[ni][0] = *(const bf16x8*)(bc + 32768 + (BH)*16384 + lB + ni*2048 + ck0); \
        bg[ni][1] = *(const bf16x8*)(bc + 32768 + (BH)*16384 + lB + ni*2048 + ck1); \
    }
#define MFMA_CL(AH, BH)                                                       \
    do {                                                                      \
        asm volatile("s_waitcnt lgkmcnt(0)" ::: "memory"); SBAR;              \
        __builtin_amdgcn_s_setprio(1);                                        \
        _Pragma("unroll") for (int mi = 0; mi < 4; mi++)                      \
            _Pragma("unroll") for (int ni = 0; ni < 2; ni++)                  \
                _Pragma("unroll") for (int kk = 0; kk < 2; kk++)              \
                    acc[(AH)*4 + mi][(BH)*2 + ni] =                           \
                        __builtin_amdgcn_mfma_f32_16x16x32_bf16(              \
                            af[mi][kk], bg[ni][kk], acc[(AH)*4 + mi][(BH)*2 + ni], 0, 0, 0); \
        __builtin_amdgcn_s_setprio(0);                                        \
    } while (0)
#define STAGE(GP, SLOT)                                                       \
    do { gld16((GP) + kn,       bn + (SLOT) + wv * 1024);                     \
         gld16((GP) + r64 + kn, bn + (SLOT) + 8192 + wv * 1024); } while (0)

    for (int t = 0; t < S; ++t) {
        char* bc = smem + (t & 1) * 65536;
        char* bn = smem + ((t & 1) ^ 1) * 65536;
        long  kn = (long)(t + 1) * 64;
        bool  st = (t + 1 < S);
        // ---- phase 0: (Al,Bl); stage Al(t+1) ----
        FRAG_A(0); FRAG_B(0);
        if (st) { STAGE(gA, 0);
                  asm volatile("s_waitcnt vmcnt(4)" ::: "memory"); }
        else    { asm volatile("s_waitcnt vmcnt(2)" ::: "memory"); }
        BARRIER;
        MFMA_CL(0, 0);
        // ---- phase 1: (Al,Bh); af kept; stage Bl(t+1) ----
        FRAG_B(1);
        if (st) { STAGE(gB, 32768);
                  asm volatile("s_waitcnt vmcnt(4)" ::: "memory"); }
        else    { asm volatile("s_waitcnt vmcnt(0)" ::: "memory"); }
        BARRIER;
        MFMA_CL(0, 1);
        // ---- phase 2: (Ah,Bh); bg kept; stage Bh(t+1); no new residency ----
        FRAG_A(1);
        if (st) STAGE(gB + 2 * r64, 49152);
        BARRIER;
        MFMA_CL(1, 1);
        // ---- phase 3: (Ah,Bl); af kept; stage Ah(t+1); publish Al,Bl(t+1) --
        FRAG_B(0);
        if (st) { STAGE(gA + 2 * r64, 16384);
                  asm volatile("s_waitcnt vmcnt(4)" ::: "memory"); }
        BARRIER;
        MFMA_CL(1, 0);
    }
    // drain: every wave passed its own lgkmcnt(0) before arriving here ->
    // all LDS reads retired; scratch reuse below is safe.
    BARRIER;
#undef FRAG_A
#undef FRAG_B
#undef MFMA_CL
#undef STAGE

    // ---------------- vectorized epilogue via per-wave LDS transpose -------
    float* sc = (float*)(smem + wv * 16384);
    int f    = (EPI == 1 || EPI == 3) ? *flag : 0;
    int j8   = lane & 7;
    int rl   = lane >> 3;
    int colg = n0 + wq * 32 + (j8 >> 2) * 128 + ((j8 * 8) & 31);
    f32x4 b0 = *(const f32x4*)(bias + colg);
    f32x4 b1 = *(const f32x4*)(bias + colg + 4);

#pragma unroll
    for (int ah = 0; ah < 2; ++ah) {
        // scatter this ah-half's 64x64 into swizzled scratch
#pragma unroll
        for (int bh = 0; bh < 2; ++bh)
#pragma unroll
            for (int ni = 0; ni < 2; ++ni)
#pragma unroll
                for (int mi = 0; mi < 4; ++mi)
#pragma unroll
                    for (int i = 0; i < 4; ++i) {
                        int r  = mi * 16 + quad * 4 + i;
                        int cl = bh * 32 + ni * 16 + rr;
                        sc[r * 64 + ((((cl >> 2) ^ (r & 15)) << 2) | (cl & 3))] =
                            acc[ah * 4 + mi][bh * 2 + ni][i];
                    }
        // readback rows, 8 consecutive cols per lane, vector stores
#pragma unroll
        for (int p = 0; p < 8; ++p) {
            int r = p * 8 + rl;
            f32x4 v0 = *(const f32x4*)(sc + r * 64 + (((2 * j8)     ^ (r & 15)) << 2));
            f32x4 v1 = *(const f32x4*)(sc + r * 64 + (((2 * j8 + 1) ^ (r & 15)) << 2));
            int row = m0 + ah * 128 + wh * 64 + r;
            v0 += b0; v1 += b1;

            if (EPI == 0) {
                bf16x8 ob;
#pragma unroll
                for (int c = 0; c < 4; c++) { ob[c] = (bf16_t)v0[c]; ob[c + 4] = (bf16_t)v1[c]; }
                *(bf16x8*)((bf16_t*)out + (long)row * N + colg) = ob;
            } else if (EPI == 1) {
                long o = (long)perm_row(row) * 512 + colg;
                if (f) {
                    f32x4 r0 = *(const f32x4*)((const float*)res + o);
                    f32x4 r1 = *(const f32x4*)((const float*)res + o + 4);
                    v0 += r0; v1 += r1;
                } else {
                    bf16x8 rb = *(const bf16x8*)((const bf16_t*)res + o);
#pragma unroll
                    for (int c = 0; c < 4; c++) { v0[c] += (float)rb[c]; v1[c] += (float)rb[c + 4]; }
                }
                *(f32x4*)((float*)out + o)     = v0;
                *(f32x4*)((float*)out + o + 4) = v1;
            } else if (EPI == 2) {
                bf16x8 ob;
#pragma unroll
                for (int c = 0; c < 4; c++) {
                    ob[c]     = (bf16_t)fast_gelu(v0[c]);
                    ob[c + 4] = (bf16_t)fast_gelu(v1[c]);
                }
                *(bf16x8*)((bf16_t*)out + (long)row * N + colg) = ob;
            } else {
                long o = (long)row * 512 + colg;
                f32x4 r0 = *(const f32x4*)((const float*)res + o);
                f32x4 r1 = *(const f32x4*)((const float*)res + o + 4);
                v0 += r0; v1 += r1;
                if (f) {
                    *(f32x4*)((float*)out + o)     = v0;
                    *(f32x4*)((float*)out + o + 4) = v1;
                } else {
                    bf16x8 ob;
#pragma unroll
                    for (int c = 0; c < 4; c++) { ob[c] = (bf16_t)v0[c]; ob[c + 4] = (bf16_t)v1[c]; }
                    *(bf16x8*)((bf16_t*)out + o) = ob;
                }
            }
        }
    }
}

// ---------------- Kernel 3: windowed attention ----------------
__global__ __launch_bounds__(256) void k_attn(const bf16_t* __restrict__ qkv,
                                              const float* __restrict__ rpb,
                                              bf16_t* __restrict__ O) {
    __shared__ float q[16][68], k[16][68], v[16][68];
    __shared__ float S[16][17];

    int blk = blockIdx.x;
    int h   = blk & 7;
    int w   = blk >> 3;
    int tid = threadIdx.x;

    int n0 = tid >> 4;
    int d0 = (tid & 15) * 4;
    // vectorized: one 8 B bf16x4 load per operand (was 12 scalar 2 B loads)
    const bf16_t* base = qkv + (long)(w * 16 + n0) * 1536 + h * 64 + d0;
    bf16x4 qv = *(const bf16x4*)(base);
    bf16x4 kv = *(const bf16x4*)(base + 512);
    bf16x4 vv = *(const bf16x4*)(base + 1024);
    f32x4 qf, kf, vf;
#pragma unroll
    for (int j = 0; j < 4; j++) {
        qf[j] = (float)qv[j] * 0.125f;
        kf[j] = (float)kv[j];
        vf[j] = (float)vv[j];
    }
    *(f32x4*)&q[n0][d0] = qf;
    *(f32x4*)&k[n0][d0] = kf;
    *(f32x4*)&v[n0][d0] = vf;
    __syncthreads();

    int i = tid >> 4, j = tid & 15;
    float s = 0.f;
#pragma unroll
    for (int d = 0; d < 64; d++) s += q[i][d] * k[j][d];

    int iy = i >> 2, ix = i & 3, jy = j >> 2, jx = j & 3;
    s += rpb[((iy - jy + 3) * 7 + (ix - jx + 3)) * 8 + h];

    int wl = w & 511;
    int wy = wl >> 5, wx = wl & 31;
    int yi = wy * 4 + iy, xi = wx * 4 + ix;
    int yj = wy * 4 + jy, xj = wx * 4 + jx;
    int ri = (yi < 60 ? 0 : (yi < 62 ? 1 : 2)) * 3 + (xi < 124 ? 0 : (xi < 126 ? 1 : 2));
    int rj = (yj < 60 ? 0 : (yj < 62 ? 1 : 2)) * 3 + (xj < 124 ? 0 : (xj < 126 ? 1 : 2));
    if (ri != rj) s -= 100.f;
    S[i][j] = s;
    __syncthreads();

    if (tid < 16) {
        float mx = -1e30f;
#pragma unroll
        for (int c = 0; c < 16; c++) mx = fmaxf(mx, S[tid][c]);
        float sum = 0.f;
#pragma unroll
        for (int c = 0; c < 16; c++) { float e = expf(S[tid][c] - mx); S[tid][c] = e; sum += e; }
        float invs = 1.f / sum;
#pragma unroll
        for (int c = 0; c < 16; c++) S[tid][c] *= invs;
    }
    __syncthreads();

#pragma unroll
    for (int t = 0; t < 4; t++) {
        int e  = tid + t * 256;
        int oi = e >> 6, od = e & 63;
        float acc = 0.f;
#pragma unroll
        for (int c = 0; c < 16; c++) acc += S[oi][c] * v[c][od];
        O[(long)(w * 16 + oi) * 512 + h * 64 + od] = (bf16_t)acc;
    }
}

// ---------------------------------------------------------------------------
extern "C" void kernel_launch(void* const* d_in, const int* in_sizes, int n_in,
                              void* d_out, int out_size, void* d_ws, size_t ws_size,
                              hipStream_t stream) {
    char* ws = (char*)d_ws;
    float*  x1   = (float*)(ws + X1_OFF);
    bf16_t* xw   = (bf16_t*)(ws + XW_OFF);    // xw -> O -> h2
    bf16_t* qkv  = (bf16_t*)(ws + QKV_OFF);   // qkv -> gelu-out a
    bf16_t* wq_b = (bf16_t*)(ws + WQ_OFF);
    bf16_t* wp_b = (bf16_t*)(ws + WP_OFF);
    bf16_t* w1_b = (bf16_t*)(ws + W1_OFF);
    bf16_t* w2_b = (bf16_t*)(ws + W2_OFF);
    float*  sv   = (float*)(ws + SV_OFF);
    int*    flag = (int*)(ws + FLAG_OFF);

    k_probe<<<1, 256, 0, stream>>>((const unsigned short*)d_in[0], 4096, flag);
    k_cvt_bf16<<<3072, 256, 0, stream>>>(d_in[3],  wq_b, 786432, flag);
    k_cvt_bf16<<<1024, 256, 0, stream>>>(d_in[6],  wp_b, 262144, flag);
    k_cvt_bf16<<<2048, 256, 0, stream>>>(d_in[10], w1_b, 524288, flag);
    k_cvt_bf16<<<2048, 256, 0, stream>>>(d_in[12], w2_b, 524288, flag);
    k_cvt_small<<<24,  256, 0, stream>>>(d_in[1], d_in[2], d_in[4], d_in[7],
                                         d_in[8], d_in[9], d_in[11], d_in[13],
                                         d_in[5], sv, flag);

    k_ln1<<<dim3(8192), dim3(256), 0, stream>>>(d_in[0], sv, sv + 512, xw, flag);
    k_gemm256<0><<<dim3(768), dim3(512), 0, stream>>>(xw, wq_b, sv + 1024, qkv, nullptr, flag, 1536, 512);
    k_attn<<<dim3(16384), dim3(256), 0, stream>>>(qkv, sv + 5632, xw /*O*/);
    k_gemm256<1><<<dim3(256), dim3(512), 0, stream>>>(xw, wp_b, sv + 2560, x1, d_in[0], flag, 512, 512);
    k_ln2<<<dim3(8192), dim3(256), 0, stream>>>(x1, sv + 3072, sv + 3584, xw /*h2*/);
    k_gemm256<2><<<dim3(512), dim3(512), 0, stream>>>(xw, w1_b, sv + 4096, qkv /*a*/, nullptr, flag, 1024, 512);
    k_gemm256<3><<<dim3(256), dim3(512), 0, stream>>>(qkv, w2_b, sv + 5120, d_out, x1, flag, 512, 1024);
}